// Round 1
// baseline (791.143 us; speedup 1.0000x reference)
//
#include <hip/hip_runtime.h>

// Problem constants
constexpr int BB = 8;
constexpr int TT = 2048;
constexpr int CC = 1024;
constexpr int HH = 64;

// ---------------------------------------------------------------------------
// Kernel 1: fused QKV projection.  q/k/v[row][h] = sum_k x[row][k]*W[k][h]
// 256 threads, 64 rows per block. thread: col = t&63, row-group rg = t>>6
// x tile staged TRANSPOSED in LDS ([K][rows], padded) so the inner loop reads
// contiguous 16 floats (b128 broadcast) per k.
// ---------------------------------------------------------------------------
constexpr int PR = 64;    // rows per block
constexpr int KC = 128;   // K chunk

__global__ __launch_bounds__(256) void qkv_proj(
    const float* __restrict__ x, const float* __restrict__ Wq,
    const float* __restrict__ Wk, const float* __restrict__ Wv,
    float* __restrict__ qo, float* __restrict__ ko, float* __restrict__ vo)
{
  __shared__ float xl[KC][PR + 4];   // +4 pad keeps 16B alignment, breaks bank stride
  const int t   = threadIdx.x;
  const int col = t & 63;
  const int rg  = t >> 6;            // 0..3 -> rows rg*16 .. rg*16+15
  const int row0 = blockIdx.x * PR;

  float aq[16], ak[16], av[16];
  #pragma unroll
  for (int r = 0; r < 16; ++r) { aq[r] = 0.f; ak[r] = 0.f; av[r] = 0.f; }

  for (int c0 = 0; c0 < CC; c0 += KC) {
    __syncthreads();   // previous iteration's reads done
    // stage 64 rows x 128 cols of x, transposed into xl[k][row]
    #pragma unroll
    for (int i = 0; i < 8; ++i) {
      int chunk = i * 256 + t;             // 2048 float4 chunks
      int r  = chunk >> 5;                 // 0..63
      int cc = (chunk & 31) << 2;          // 0..124
      float4 xv = *reinterpret_cast<const float4*>(&x[(row0 + r) * CC + c0 + cc]);
      xl[cc + 0][r] = xv.x;
      xl[cc + 1][r] = xv.y;
      xl[cc + 2][r] = xv.z;
      xl[cc + 3][r] = xv.w;
    }
    __syncthreads();   // writes visible

    #pragma unroll 2
    for (int kk = 0; kk < KC; ++kk) {
      float wq = Wq[(c0 + kk) * HH + col];
      float wk = Wk[(c0 + kk) * HH + col];
      float wv = Wv[(c0 + kk) * HH + col];
      const float* xr = &xl[kk][rg * 16];
      float4 xa = *reinterpret_cast<const float4*>(xr + 0);
      float4 xb = *reinterpret_cast<const float4*>(xr + 4);
      float4 xc = *reinterpret_cast<const float4*>(xr + 8);
      float4 xd = *reinterpret_cast<const float4*>(xr + 12);
      float xv[16] = {xa.x, xa.y, xa.z, xa.w, xb.x, xb.y, xb.z, xb.w,
                      xc.x, xc.y, xc.z, xc.w, xd.x, xd.y, xd.z, xd.w};
      #pragma unroll
      for (int r = 0; r < 16; ++r) {
        aq[r] = fmaf(xv[r], wq, aq[r]);
        ak[r] = fmaf(xv[r], wk, ak[r]);
        av[r] = fmaf(xv[r], wv, av[r]);
      }
    }
  }
  #pragma unroll
  for (int r = 0; r < 16; ++r) {
    int orow = row0 + rg * 16 + r;
    qo[orow * HH + col] = aq[r];
    ko[orow * HH + col] = ak[r];
    vo[orow * HH + col] = av[r];
  }
}

// ---------------------------------------------------------------------------
// Kernel 2: causal flash attention, fp32.
// grid = B * (T/64) = 256 blocks (1 per CU), 256 threads = 4 waves.
// Each lane owns one q row (q + acc in registers, statically indexed).
// The 4 waves split the key-tile loop (kt = w, w+4, ...); partial online
// softmax states are merged through LDS at the end.
// Scores use a finite sentinel NEG instead of -inf: no NaN paths for
// fully-masked tiles (their m stays NEG -> weight exp2(NEG-m*) == 0).
// ---------------------------------------------------------------------------
constexpr int KT = 32;                       // key tile
constexpr float NEG = -30000.0f;             // masked-logit sentinel (log2 units)
constexpr float SC  = 0.045084220027780106f; // (1/sqrt(1024)) * log2(e)

struct SMemA { float kl[4][KT][HH]; float vl[4][KT][HH]; float sl[4][KT][64]; };
struct SMemB { float macc[4][64][68]; float mm[4][64]; float ml[4][64]; };
union  SMemU { SMemA a; SMemB b; };

__global__ __launch_bounds__(256) void attn_fwd(
    const float* __restrict__ q, const float* __restrict__ k,
    const float* __restrict__ v, float* __restrict__ out)
{
  __shared__ SMemU sm;
  const int t    = threadIdx.x;
  const int lane = t & 63;
  const int w    = t >> 6;                 // wave 0..3
  const int qt   = blockIdx.x & 31;        // q tile within batch (T/64 = 32)
  const int b    = blockIdx.x >> 5;
  const int base = b * TT * HH;
  const int qrow = qt * 64 + lane;         // row within batch

  // q row -> registers (16 x float4, static indexing only)
  float4 q4[16];
  const float* qp = q + base + qrow * HH;
  #pragma unroll
  for (int j = 0; j < 16; ++j) q4[j] = reinterpret_cast<const float4*>(qp)[j];

  float4 acc4[16];
  #pragma unroll
  for (int j = 0; j < 16; ++j) acc4[j] = make_float4(0.f, 0.f, 0.f, 0.f);
  float m = NEG, l = 0.f;

  const int ktmax = 2 * qt + 1;            // inclusive causal key-tile limit
  for (int kt = w; kt <= ktmax; kt += 4) {
    const float* kp = k + base + kt * KT * HH;
    const float* vp = v + base + kt * KT * HH;

    // WAR: previous tile's LDS reads drained before overwrite (same-wave only)
    asm volatile("s_waitcnt lgkmcnt(0)" ::: "memory");
    #pragma unroll
    for (int i = 0; i < 8; ++i) {
      int chunk = i * 64 + lane;           // 512 float4 chunks per tile
      int r  = chunk >> 4;
      int hh = (chunk & 15) << 2;
      *reinterpret_cast<float4*>(&sm.a.kl[w][r][hh]) =
          *reinterpret_cast<const float4*>(&kp[r * HH + hh]);
      *reinterpret_cast<float4*>(&sm.a.vl[w][r][hh]) =
          *reinterpret_cast<const float4*>(&vp[r * HH + hh]);
    }
    // all 64 lanes' ds_writes complete -> tile visible wave-wide
    asm volatile("s_waitcnt lgkmcnt(0)" ::: "memory");
    __builtin_amdgcn_wave_barrier();

    // ---- QK^T: 32 scores per lane; scores parked in LDS (same-lane slot) ----
    float mtile = NEG;
    #pragma unroll 4
    for (int c = 0; c < KT; ++c) {
      float d0 = 0.f, d1 = 0.f, d2 = 0.f, d3 = 0.f;
      #pragma unroll
      for (int j = 0; j < 16; ++j) {
        float4 kv = *reinterpret_cast<const float4*>(&sm.a.kl[w][c][j * 4]);
        d0 = fmaf(q4[j].x, kv.x, d0);
        d1 = fmaf(q4[j].y, kv.y, d1);
        d2 = fmaf(q4[j].z, kv.z, d2);
        d3 = fmaf(q4[j].w, kv.w, d3);
      }
      float s = ((d0 + d1) + (d2 + d3)) * SC;
      int kc = kt * KT + c;
      s = (kc <= qrow) ? s : NEG;          // causal mask (diagonal included)
      mtile = fmaxf(mtile, s);
      sm.a.sl[w][c][lane] = s;
    }

    // ---- online softmax update + PV ----
    float mnew = fmaxf(m, mtile);
    float corr = exp2f(m - mnew);          // m==mnew==NEG -> exp2(0)=1, acc==0: benign
    #pragma unroll
    for (int j = 0; j < 16; ++j) {
      acc4[j].x *= corr; acc4[j].y *= corr; acc4[j].z *= corr; acc4[j].w *= corr;
    }
    float psum = 0.f;
    #pragma unroll 2
    for (int c = 0; c < KT; ++c) {
      float p = exp2f(sm.a.sl[w][c][lane] - mnew);
      psum += p;
      #pragma unroll
      for (int j = 0; j < 16; ++j) {
        float4 vv = *reinterpret_cast<const float4*>(&sm.a.vl[w][c][j * 4]);
        acc4[j].x = fmaf(p, vv.x, acc4[j].x);
        acc4[j].y = fmaf(p, vv.y, acc4[j].y);
        acc4[j].z = fmaf(p, vv.z, acc4[j].z);
        acc4[j].w = fmaf(p, vv.w, acc4[j].w);
      }
    }
    l = l * corr + psum;
    m = mnew;
  }

  // ---- merge the 4 per-wave partial states (union re-use of LDS) ----
  __syncthreads();                          // everyone done with SMemA
  #pragma unroll
  for (int j = 0; j < 16; ++j)
    *reinterpret_cast<float4*>(&sm.b.macc[w][lane][j * 4]) = acc4[j];
  sm.b.mm[w][lane] = m;
  sm.b.ml[w][lane] = l;
  __syncthreads();

  if (w == 0) {
    float m0 = sm.b.mm[0][lane], m1 = sm.b.mm[1][lane];
    float m2 = sm.b.mm[2][lane], m3 = sm.b.mm[3][lane];
    float ms = fmaxf(fmaxf(m0, m1), fmaxf(m2, m3));   // ms finite: wave0 always ran tile 0
    float c0 = exp2f(m0 - ms), c1 = exp2f(m1 - ms);
    float c2 = exp2f(m2 - ms), c3 = exp2f(m3 - ms);
    float lsum = sm.b.ml[0][lane] * c0 + sm.b.ml[1][lane] * c1 +
                 sm.b.ml[2][lane] * c2 + sm.b.ml[3][lane] * c3;
    float inv = 1.0f / lsum;
    float* op = out + base + qrow * HH;
    #pragma unroll
    for (int j = 0; j < 16; ++j) {
      float4 a0 = *reinterpret_cast<const float4*>(&sm.b.macc[0][lane][j * 4]);
      float4 a1 = *reinterpret_cast<const float4*>(&sm.b.macc[1][lane][j * 4]);
      float4 a2 = *reinterpret_cast<const float4*>(&sm.b.macc[2][lane][j * 4]);
      float4 a3 = *reinterpret_cast<const float4*>(&sm.b.macc[3][lane][j * 4]);
      float4 r;
      r.x = (a0.x * c0 + a1.x * c1 + a2.x * c2 + a3.x * c3) * inv;
      r.y = (a0.y * c0 + a1.y * c1 + a2.y * c2 + a3.y * c3) * inv;
      r.z = (a0.z * c0 + a1.z * c1 + a2.z * c2 + a3.z * c3) * inv;
      r.w = (a0.w * c0 + a1.w * c1 + a2.w * c2 + a3.w * c3) * inv;
      *reinterpret_cast<float4*>(&op[j * 4]) = r;
    }
  }
}

// ---------------------------------------------------------------------------
extern "C" void kernel_launch(void* const* d_in, const int* in_sizes, int n_in,
                              void* d_out, int out_size, void* d_ws, size_t ws_size,
                              hipStream_t stream) {
  const float* x  = (const float*)d_in[0];
  const float* Wq = (const float*)d_in[1];
  const float* Wk = (const float*)d_in[2];
  const float* Wv = (const float*)d_in[3];
  float* outp = (float*)d_out;

  float* qws = (float*)d_ws;                       // [B*T, 64] fp32
  float* kws = qws + (size_t)BB * TT * HH;
  float* vws = kws + (size_t)BB * TT * HH;

  qkv_proj<<<(BB * TT) / PR, 256, 0, stream>>>(x, Wq, Wk, Wv, qws, kws, vws);
  attn_fwd<<<BB * (TT / 64), 256, 0, stream>>>(qws, kws, vws, outp);
}

// Round 2
// 104.237 us; speedup vs baseline: 7.5898x; 7.5898x over previous
//
#include <hip/hip_runtime.h>

constexpr int BB = 8, TT = 2048, CC = 1024, HH = 64;
constexpr int BT = BB * TT;                         // 16384 rows total
constexpr float SC  = 0.045084220027780106f;        // (1/sqrt(1024)) * log2(e)
constexpr float NEG = -30000.0f;

typedef float  f32x4  __attribute__((ext_vector_type(4)));
typedef short  short8 __attribute__((ext_vector_type(8)));

union Frag { short8 s8; unsigned u[4]; uint4 u4; };

static __device__ inline unsigned short f2bf(float f) {        // RNE fp32->bf16
  unsigned u = __builtin_bit_cast(unsigned, f);
  u += 0x7fffu + ((u >> 16) & 1u);
  return (unsigned short)(u >> 16);
}
static __device__ inline unsigned pk2(float a, float b) {      // pack 2 bf16 (RNE)
  unsigned ua = __builtin_bit_cast(unsigned, a); ua += 0x7fffu + ((ua >> 16) & 1u);
  unsigned ub = __builtin_bit_cast(unsigned, b); ub += 0x7fffu + ((ub >> 16) & 1u);
  return (ua >> 16) | (ub & 0xffff0000u);
}
static __device__ inline unsigned pk2r(float a, float b) {     // pack, cheap round (pos values)
  unsigned ua = __builtin_bit_cast(unsigned, a) + 0x8000u;
  unsigned ub = __builtin_bit_cast(unsigned, b) + 0x8000u;
  return (ua >> 16) | (ub & 0xffff0000u);
}

// Assumed (lane-group g, slot j) -> k map used CONSISTENTLY on both MFMA input
// operands: k = 4*g + (j&3) + 16*(j>>2). Any hardware k-map yields correct
// results as long as A and B use identical maps (permutation consistency).
// C/D layout (HW-verified): col = lane&15, row = (lane>>4)*4 + reg.

// ---------------------------------------------------------------------------
// Kernel 0: W -> bf16, written in fragment-slot order: wt[(mat*64+n)*1024 + pos(k)]
// pos(k) = (k>>5)*32 + ((k&15)>>2)*8 + ((k>>4)&1)*4 + (k&3)
// ---------------------------------------------------------------------------
__global__ __launch_bounds__(256) void wcvt(
    const float* __restrict__ Wq, const float* __restrict__ Wk,
    const float* __restrict__ Wv, unsigned short* __restrict__ wt)
{
  const int bid = blockIdx.x;              // 0..191 = mat*64 + n
  const int mat = bid >> 6, n = bid & 63;
  const float* W = (mat == 0) ? Wq : ((mat == 1) ? Wk : Wv);
  unsigned short* o = wt + (size_t)bid * 1024;
  for (int k = threadIdx.x; k < 1024; k += 256) {
    float v = W[k * 64 + n];
    int pos = ((k >> 5) << 5) + (((k & 15) >> 2) << 3) + (((k >> 4) & 1) << 2) + (k & 3);
    o[pos] = f2bf(v);
  }
}

// ---------------------------------------------------------------------------
// Kernel 1: QKV projection via MFMA. grid=256, 512 thr (8 waves):
// 4 row-groups (16 rows) x 2 K-halves; LDS merge of the K-split partials.
// x A-frags straight from global fp32 (full-cache-line wave pattern), cvt in reg.
// Outputs (fragment-slot order): qb,kb row-major [row][64]; vt transposed [d][BT].
// ---------------------------------------------------------------------------
__global__ __launch_bounds__(512) void qkv_proj(
    const float* __restrict__ x, const unsigned short* __restrict__ wt,
    unsigned short* __restrict__ qb, unsigned short* __restrict__ kb,
    unsigned short* __restrict__ vt)
{
  __shared__ float pacc[4][12][64][4];     // 48 KB
  const int tid = threadIdx.x, lane = tid & 63, w = tid >> 6;
  const int rg = w >> 1, kh = w & 1;
  const int l4 = lane >> 4, li = lane & 15;
  const int m0 = blockIdx.x * 64 + rg * 16;

  f32x4 acc[12];
  #pragma unroll
  for (int f = 0; f < 12; ++f) acc[f] = (f32x4){0.f, 0.f, 0.f, 0.f};

  const float* xp = x + (size_t)(m0 + li) * CC;
  const unsigned short* wbase = wt + (size_t)li * 1024 + l4 * 8;

  #pragma unroll 2
  for (int ch = 0; ch < 8; ++ch) {
    const int k0 = kh * 512 + ch * 64;
    Frag xa0, xa1;
    {
      float4 fa = *(const float4*)(xp + k0 + l4 * 4);
      float4 fb = *(const float4*)(xp + k0 + l4 * 4 + 16);
      float4 fc = *(const float4*)(xp + k0 + 32 + l4 * 4);
      float4 fd = *(const float4*)(xp + k0 + 32 + l4 * 4 + 16);
      xa0.u[0] = pk2(fa.x, fa.y); xa0.u[1] = pk2(fa.z, fa.w);
      xa0.u[2] = pk2(fb.x, fb.y); xa0.u[3] = pk2(fb.z, fb.w);
      xa1.u[0] = pk2(fc.x, fc.y); xa1.u[1] = pk2(fc.z, fc.w);
      xa1.u[2] = pk2(fd.x, fd.y); xa1.u[3] = pk2(fd.z, fd.w);
    }
    #pragma unroll
    for (int f = 0; f < 12; ++f) {
      Frag b0, b1;
      const unsigned short* wp = wbase + (size_t)f * 16 * 1024 + k0;
      b0.u4 = *(const uint4*)(wp);
      b1.u4 = *(const uint4*)(wp + 32);
      acc[f] = __builtin_amdgcn_mfma_f32_16x16x32_bf16(xa0.s8, b0.s8, acc[f], 0, 0, 0);
      acc[f] = __builtin_amdgcn_mfma_f32_16x16x32_bf16(xa1.s8, b1.s8, acc[f], 0, 0, 0);
    }
  }

  if (kh == 1) {
    #pragma unroll
    for (int f = 0; f < 12; ++f) *(f32x4*)&pacc[rg][f][lane][0] = acc[f];
  }
  __syncthreads();
  if (kh == 0) {
    #pragma unroll
    for (int f = 0; f < 12; ++f) acc[f] += *(const f32x4*)&pacc[rg][f][lane][0];

    const int pc = ((li >> 2) << 3) + (li & 3);
    #pragma unroll
    for (int f = 0; f < 4; ++f) {
      const int col = ((f >> 1) << 5) + ((f & 1) << 2) + pc;
      #pragma unroll
      for (int r = 0; r < 4; ++r) {
        const size_t row = m0 + 4 * l4 + r;
        qb[row * 64 + col] = f2bf(acc[f][r]);
        kb[row * 64 + col] = f2bf(acc[4 + f][r]);
      }
    }
    const int vb = (m0 & ~31) + (((m0 >> 4) & 1) << 2) + (l4 << 3);
    #pragma unroll
    for (int f = 0; f < 4; ++f) {
      const int d = (f << 4) + li;
      unsigned lo = pk2(acc[8 + f][0], acc[8 + f][1]);
      unsigned hi = pk2(acc[8 + f][2], acc[8 + f][3]);
      *(uint2*)&vt[(size_t)d * BT + vb] = make_uint2(lo, hi);
    }
  }
}

// ---------------------------------------------------------------------------
// Kernel 2: causal flash attention, bf16 MFMA.
// grid = 8 batches x 32 pairs = 256 blocks, 512 thr (8 waves).
// Block handles q-groups (pr, 63-pr) [32 rows each]; wave = (16-row half, key parity).
// Swapped QK^T -> lane owns one q-row; in-register softmax; parity merge in LDS.
// ---------------------------------------------------------------------------
__global__ __launch_bounds__(512) void attn_fwd(
    const unsigned short* __restrict__ qb, const unsigned short* __restrict__ kb,
    const unsigned short* __restrict__ vt, float* __restrict__ out)
{
  __shared__ float oacc[8][16][64];        // 32 KB
  __shared__ float ml[8][2][16];
  const int tid = threadIdx.x, lane = tid & 63, w = tid >> 6;
  const int par = w & 1, qgh = w >> 1;
  const int pr = blockIdx.x & 31, b = blockIdx.x >> 5;
  const int g32 = (qgh < 2) ? pr : 63 - pr;
  const int q0 = g32 * 32 + (qgh & 1) * 16;           // within batch
  const int ktmax = q0 >> 5;
  const int bT = b * TT;
  const int l4 = lane >> 4, li = lane & 15;
  const int qrow = q0 + li;

  Frag qf0, qf1;
  {
    const unsigned short* qp = qb + (size_t)(bT + q0 + li) * 64 + l4 * 8;
    qf0.u4 = *(const uint4*)(qp);
    qf1.u4 = *(const uint4*)(qp + 32);
  }

  f32x4 acc0 = {0,0,0,0}, acc1 = {0,0,0,0}, acc2 = {0,0,0,0}, acc3 = {0,0,0,0};
  float mreg = NEG, lsum = 0.f;

  for (int kt = par; kt <= ktmax; kt += 2) {
    const int key0 = kt * 32;
    const unsigned short* kp = kb + (size_t)(bT + key0 + li) * 64 + l4 * 8;
    Frag k00, k01, k10, k11;
    k00.u4 = *(const uint4*)(kp);
    k01.u4 = *(const uint4*)(kp + 32);
    k10.u4 = *(const uint4*)(kp + 16 * 64);
    k11.u4 = *(const uint4*)(kp + 16 * 64 + 32);
    const unsigned short* vp = vt + (size_t)li * BT + bT + key0 + l4 * 8;
    Frag v0, v1, v2, v3;
    v0.u4 = *(const uint4*)(vp);
    v1.u4 = *(const uint4*)(vp + (size_t)16 * BT);
    v2.u4 = *(const uint4*)(vp + (size_t)32 * BT);
    v3.u4 = *(const uint4*)(vp + (size_t)48 * BT);

    f32x4 s0 = {0,0,0,0}, s1 = {0,0,0,0};
    s0 = __builtin_amdgcn_mfma_f32_16x16x32_bf16(k00.s8, qf0.s8, s0, 0, 0, 0);
    s0 = __builtin_amdgcn_mfma_f32_16x16x32_bf16(k01.s8, qf1.s8, s0, 0, 0, 0);
    s1 = __builtin_amdgcn_mfma_f32_16x16x32_bf16(k10.s8, qf0.s8, s1, 0, 0, 0);
    s1 = __builtin_amdgcn_mfma_f32_16x16x32_bf16(k11.s8, qf1.s8, s1, 0, 0, 0);

    float sv[8];
    float pm = NEG;
    #pragma unroll
    for (int r = 0; r < 4; ++r) {
      const int kA = key0 + 4 * l4 + r;
      float a = s0[r] * SC; a = (kA       <= qrow) ? a : NEG;
      float c = s1[r] * SC; c = (kA + 16  <= qrow) ? c : NEG;
      sv[r] = a; sv[r + 4] = c;
      pm = fmaxf(pm, fmaxf(a, c));
    }
    pm = fmaxf(pm, __shfl_xor(pm, 16));
    pm = fmaxf(pm, __shfl_xor(pm, 32));

    if (__any(pm > mreg + 8.0f)) {                     // defer-max rescale
      const float mnew = fmaxf(mreg, pm);
      const float corr = exp2f(mreg - mnew);
      lsum *= corr;
      #pragma unroll
      for (int r = 0; r < 4; ++r) {
        const float cr = __shfl(corr, 4 * l4 + r);
        acc0[r] *= cr; acc1[r] *= cr; acc2[r] *= cr; acc3[r] *= cr;
      }
      mreg = mnew;
    }

    float p[8], psum = 0.f;
    #pragma unroll
    for (int j = 0; j < 8; ++j) { p[j] = exp2f(sv[j] - mreg); psum += p[j]; }
    psum += __shfl_xor(psum, 16);
    psum += __shfl_xor(psum, 32);
    lsum += psum;

    Frag pf;
    pf.u[0] = pk2r(p[0], p[1]); pf.u[1] = pk2r(p[2], p[3]);
    pf.u[2] = pk2r(p[4], p[5]); pf.u[3] = pk2r(p[6], p[7]);

    acc0 = __builtin_amdgcn_mfma_f32_16x16x32_bf16(pf.s8, v0.s8, acc0, 0, 0, 0);
    acc1 = __builtin_amdgcn_mfma_f32_16x16x32_bf16(pf.s8, v1.s8, acc1, 0, 0, 0);
    acc2 = __builtin_amdgcn_mfma_f32_16x16x32_bf16(pf.s8, v2.s8, acc2, 0, 0, 0);
    acc3 = __builtin_amdgcn_mfma_f32_16x16x32_bf16(pf.s8, v3.s8, acc3, 0, 0, 0);
  }

  // ---- merge parity-partner waves ----
  if (par == 1) {
    #pragma unroll
    for (int r = 0; r < 4; ++r) {
      const int row = 4 * l4 + r;
      oacc[w][row][li]      = acc0[r];
      oacc[w][row][16 + li] = acc1[r];
      oacc[w][row][32 + li] = acc2[r];
      oacc[w][row][48 + li] = acc3[r];
    }
    if (l4 == 0) { ml[w][0][li] = mreg; ml[w][1][li] = lsum; }
  }
  __syncthreads();
  if (par == 0) {
    const float m1 = ml[w + 1][0][li], l1 = ml[w + 1][1][li];
    const float ms = fmaxf(mreg, m1);
    float a0 = exp2f(mreg - ms), a1 = exp2f(m1 - ms);
    const float L = lsum * a0 + l1 * a1;
    const float inv = 1.0f / L;
    a0 *= inv; a1 *= inv;
    float* op = out + (size_t)(bT + q0) * 64;
    #pragma unroll
    for (int r = 0; r < 4; ++r) {
      const float w0 = __shfl(a0, 4 * l4 + r);
      const float w1 = __shfl(a1, 4 * l4 + r);
      const int row = 4 * l4 + r;
      op[row * 64 + li]      = acc0[r] * w0 + oacc[w + 1][row][li]      * w1;
      op[row * 64 + 16 + li] = acc1[r] * w0 + oacc[w + 1][row][16 + li] * w1;
      op[row * 64 + 32 + li] = acc2[r] * w0 + oacc[w + 1][row][32 + li] * w1;
      op[row * 64 + 48 + li] = acc3[r] * w0 + oacc[w + 1][row][48 + li] * w1;
    }
  }
}

// ---------------------------------------------------------------------------
extern "C" void kernel_launch(void* const* d_in, const int* in_sizes, int n_in,
                              void* d_out, int out_size, void* d_ws, size_t ws_size,
                              hipStream_t stream) {
  const float* x  = (const float*)d_in[0];
  const float* Wq = (const float*)d_in[1];
  const float* Wk = (const float*)d_in[2];
  const float* Wv = (const float*)d_in[3];
  float* outp = (float*)d_out;

  unsigned short* wt = (unsigned short*)d_ws;        // [3*64][1024]  = 196608
  unsigned short* qb = wt + 196608;                  // [BT][64]
  unsigned short* kb = qb + (size_t)BT * 64;         // [BT][64]
  unsigned short* vt = kb + (size_t)BT * 64;         // [64][BT]

  wcvt<<<192, 256, 0, stream>>>(Wq, Wk, Wv, wt);
  qkv_proj<<<256, 512, 0, stream>>>(x, wt, qb, kb, vt);
  attn_fwd<<<256, 512, 0, stream>>>(qb, kb, vt, outp);
}

// Round 3
// 96.522 us; speedup vs baseline: 8.1965x; 1.0799x over previous
//
#include <hip/hip_runtime.h>

constexpr int BB = 8, TT = 2048, CC = 1024, HH = 64;
constexpr int BT = BB * TT;                         // 16384 rows total
constexpr float SC  = 0.045084220027780106f;        // (1/sqrt(1024)) * log2(e)
constexpr float NEG = -30000.0f;

typedef float  f32x4  __attribute__((ext_vector_type(4)));
typedef short  short8 __attribute__((ext_vector_type(8)));

union Frag { short8 s8; unsigned u[4]; uint4 u4; };

static __device__ inline unsigned short f2bf(float f) {        // RNE fp32->bf16
  unsigned u = __builtin_bit_cast(unsigned, f);
  u += 0x7fffu + ((u >> 16) & 1u);
  return (unsigned short)(u >> 16);
}
static __device__ inline unsigned pk2(float a, float b) {      // pack 2 bf16 (RNE)
  unsigned ua = __builtin_bit_cast(unsigned, a); ua += 0x7fffu + ((ua >> 16) & 1u);
  unsigned ub = __builtin_bit_cast(unsigned, b); ub += 0x7fffu + ((ub >> 16) & 1u);
  return (ua >> 16) | (ub & 0xffff0000u);
}
static __device__ inline unsigned pk2r(float a, float b) {     // pack, cheap round (pos values)
  unsigned ua = __builtin_bit_cast(unsigned, a) + 0x8000u;
  unsigned ub = __builtin_bit_cast(unsigned, b) + 0x8000u;
  return (ua >> 16) | (ub & 0xffff0000u);
}

// Assumed (lane-group g, slot j) -> k map used CONSISTENTLY on both MFMA input
// operands: k = 4*g + (j&3) + 16*(j>>2). Correct for any hardware k-map as
// long as A and B use identical maps (permutation consistency).
// C/D layout (HW-verified): col = lane&15, row = (lane>>4)*4 + reg.

// ---------------------------------------------------------------------------
// Kernel 0: W -> bf16, written in fragment-slot order: wt[(mat*64+n)*1024 + pos(k)]
// pos(k) = (k>>5)*32 + ((k&15)>>2)*8 + ((k>>4)&1)*4 + (k&3)
// ---------------------------------------------------------------------------
__global__ __launch_bounds__(256) void wcvt(
    const float* __restrict__ Wq, const float* __restrict__ Wk,
    const float* __restrict__ Wv, unsigned short* __restrict__ wt)
{
  const int bid = blockIdx.x;              // 0..191 = mat*64 + n
  const int mat = bid >> 6, n = bid & 63;
  const float* W = (mat == 0) ? Wq : ((mat == 1) ? Wk : Wv);
  unsigned short* o = wt + (size_t)bid * 1024;
  for (int k = threadIdx.x; k < 1024; k += 256) {
    float v = W[k * 64 + n];
    int pos = ((k >> 5) << 5) + (((k & 15) >> 2) << 3) + (((k >> 4) & 1) << 2) + (k & 3);
    o[pos] = f2bf(v);
  }
}

// ---------------------------------------------------------------------------
// Kernel 1: QKV projection via MFMA.
// grid = 512 blocks (32 rows each), 512 thr = 8 waves:
//   wave = (row-group rg 0..1 [16 rows], K-quarter kq 0..3 [K=256]).
// 4-way K-split partials merged through LDS; kq==0 waves write outputs.
// 72 KB LDS -> 2 blocks/CU = 4 waves/SIMD (2x round-2 occupancy).
// Outputs (fragment-slot order): qb,kb row-major [row][64]; vt transposed [d][BT].
// ---------------------------------------------------------------------------
__global__ __launch_bounds__(512) void qkv_proj(
    const float* __restrict__ x, const unsigned short* __restrict__ wt,
    unsigned short* __restrict__ qb, unsigned short* __restrict__ kb,
    unsigned short* __restrict__ vt)
{
  __shared__ float pacc[2][3][12][64][4];  // 72 KB
  const int tid = threadIdx.x, lane = tid & 63, w = tid >> 6;
  const int rg = w >> 2, kq = w & 3;
  const int l4 = lane >> 4, li = lane & 15;
  const int m0 = blockIdx.x * 32 + rg * 16;

  f32x4 acc[12];
  #pragma unroll
  for (int f = 0; f < 12; ++f) acc[f] = (f32x4){0.f, 0.f, 0.f, 0.f};

  const float* xp = x + (size_t)(m0 + li) * CC;
  const unsigned short* wbase = wt + (size_t)li * 1024 + l4 * 8;

  #pragma unroll 2
  for (int ch = 0; ch < 4; ++ch) {
    const int k0 = kq * 256 + ch * 64;
    Frag xa0, xa1;
    {
      float4 fa = *(const float4*)(xp + k0 + l4 * 4);
      float4 fb = *(const float4*)(xp + k0 + l4 * 4 + 16);
      float4 fc = *(const float4*)(xp + k0 + 32 + l4 * 4);
      float4 fd = *(const float4*)(xp + k0 + 32 + l4 * 4 + 16);
      xa0.u[0] = pk2(fa.x, fa.y); xa0.u[1] = pk2(fa.z, fa.w);
      xa0.u[2] = pk2(fb.x, fb.y); xa0.u[3] = pk2(fb.z, fb.w);
      xa1.u[0] = pk2(fc.x, fc.y); xa1.u[1] = pk2(fc.z, fc.w);
      xa1.u[2] = pk2(fd.x, fd.y); xa1.u[3] = pk2(fd.z, fd.w);
    }
    #pragma unroll
    for (int f = 0; f < 12; ++f) {
      Frag b0, b1;
      const unsigned short* wp = wbase + (size_t)f * 16 * 1024 + k0;
      b0.u4 = *(const uint4*)(wp);
      b1.u4 = *(const uint4*)(wp + 32);
      acc[f] = __builtin_amdgcn_mfma_f32_16x16x32_bf16(xa0.s8, b0.s8, acc[f], 0, 0, 0);
      acc[f] = __builtin_amdgcn_mfma_f32_16x16x32_bf16(xa1.s8, b1.s8, acc[f], 0, 0, 0);
    }
  }

  if (kq != 0) {
    #pragma unroll
    for (int f = 0; f < 12; ++f) *(f32x4*)&pacc[rg][kq - 1][f][lane][0] = acc[f];
  }
  __syncthreads();
  if (kq == 0) {
    #pragma unroll
    for (int f = 0; f < 12; ++f) {
      acc[f] += *(const f32x4*)&pacc[rg][0][f][lane][0];
      acc[f] += *(const f32x4*)&pacc[rg][1][f][lane][0];
      acc[f] += *(const f32x4*)&pacc[rg][2][f][lane][0];
    }

    const int pc = ((li >> 2) << 3) + (li & 3);
    #pragma unroll
    for (int f = 0; f < 4; ++f) {
      const int col = ((f >> 1) << 5) + ((f & 1) << 2) + pc;
      #pragma unroll
      for (int r = 0; r < 4; ++r) {
        const size_t row = m0 + 4 * l4 + r;
        qb[row * 64 + col] = f2bf(acc[f][r]);
        kb[row * 64 + col] = f2bf(acc[4 + f][r]);
      }
    }
    const int vb = (m0 & ~31) + (((m0 >> 4) & 1) << 2) + (l4 << 3);
    #pragma unroll
    for (int f = 0; f < 4; ++f) {
      const int d = (f << 4) + li;
      unsigned lo = pk2(acc[8 + f][0], acc[8 + f][1]);
      unsigned hi = pk2(acc[8 + f][2], acc[8 + f][3]);
      *(uint2*)&vt[(size_t)d * BT + vb] = make_uint2(lo, hi);
    }
  }
}

// ---------------------------------------------------------------------------
// Kernel 2: causal flash attention, bf16 MFMA. (unchanged from round 2)
// grid = 8 batches x 32 pairs = 256 blocks, 512 thr (8 waves).
// Block handles q-groups (pr, 63-pr) [32 rows each]; wave = (16-row half, key parity).
// Swapped QK^T -> lane owns one q-row; in-register softmax; parity merge in LDS.
// ---------------------------------------------------------------------------
__global__ __launch_bounds__(512) void attn_fwd(
    const unsigned short* __restrict__ qb, const unsigned short* __restrict__ kb,
    const unsigned short* __restrict__ vt, float* __restrict__ out)
{
  __shared__ float oacc[8][16][64];        // 32 KB
  __shared__ float ml[8][2][16];
  const int tid = threadIdx.x, lane = tid & 63, w = tid >> 6;
  const int par = w & 1, qgh = w >> 1;
  const int pr = blockIdx.x & 31, b = blockIdx.x >> 5;
  const int g32 = (qgh < 2) ? pr : 63 - pr;
  const int q0 = g32 * 32 + (qgh & 1) * 16;           // within batch
  const int ktmax = q0 >> 5;
  const int bT = b * TT;
  const int l4 = lane >> 4, li = lane & 15;
  const int qrow = q0 + li;

  Frag qf0, qf1;
  {
    const unsigned short* qp = qb + (size_t)(bT + q0 + li) * 64 + l4 * 8;
    qf0.u4 = *(const uint4*)(qp);
    qf1.u4 = *(const uint4*)(qp + 32);
  }

  f32x4 acc0 = {0,0,0,0}, acc1 = {0,0,0,0}, acc2 = {0,0,0,0}, acc3 = {0,0,0,0};
  float mreg = NEG, lsum = 0.f;

  for (int kt = par; kt <= ktmax; kt += 2) {
    const int key0 = kt * 32;
    const unsigned short* kp = kb + (size_t)(bT + key0 + li) * 64 + l4 * 8;
    Frag k00, k01, k10, k11;
    k00.u4 = *(const uint4*)(kp);
    k01.u4 = *(const uint4*)(kp + 32);
    k10.u4 = *(const uint4*)(kp + 16 * 64);
    k11.u4 = *(const uint4*)(kp + 16 * 64 + 32);
    const unsigned short* vp = vt + (size_t)li * BT + bT + key0 + l4 * 8;
    Frag v0, v1, v2, v3;
    v0.u4 = *(const uint4*)(vp);
    v1.u4 = *(const uint4*)(vp + (size_t)16 * BT);
    v2.u4 = *(const uint4*)(vp + (size_t)32 * BT);
    v3.u4 = *(const uint4*)(vp + (size_t)48 * BT);

    f32x4 s0 = {0,0,0,0}, s1 = {0,0,0,0};
    s0 = __builtin_amdgcn_mfma_f32_16x16x32_bf16(k00.s8, qf0.s8, s0, 0, 0, 0);
    s0 = __builtin_amdgcn_mfma_f32_16x16x32_bf16(k01.s8, qf1.s8, s0, 0, 0, 0);
    s1 = __builtin_amdgcn_mfma_f32_16x16x32_bf16(k10.s8, qf0.s8, s1, 0, 0, 0);
    s1 = __builtin_amdgcn_mfma_f32_16x16x32_bf16(k11.s8, qf1.s8, s1, 0, 0, 0);

    float sv[8];
    float pm = NEG;
    #pragma unroll
    for (int r = 0; r < 4; ++r) {
      const int kA = key0 + 4 * l4 + r;
      float a = s0[r] * SC; a = (kA       <= qrow) ? a : NEG;
      float c = s1[r] * SC; c = (kA + 16  <= qrow) ? c : NEG;
      sv[r] = a; sv[r + 4] = c;
      pm = fmaxf(pm, fmaxf(a, c));
    }
    pm = fmaxf(pm, __shfl_xor(pm, 16));
    pm = fmaxf(pm, __shfl_xor(pm, 32));

    if (__any(pm > mreg + 8.0f)) {                     // defer-max rescale
      const float mnew = fmaxf(mreg, pm);
      const float corr = exp2f(mreg - mnew);
      lsum *= corr;
      #pragma unroll
      for (int r = 0; r < 4; ++r) {
        const float cr = __shfl(corr, 4 * l4 + r);
        acc0[r] *= cr; acc1[r] *= cr; acc2[r] *= cr; acc3[r] *= cr;
      }
      mreg = mnew;
    }

    float p[8], psum = 0.f;
    #pragma unroll
    for (int j = 0; j < 8; ++j) { p[j] = exp2f(sv[j] - mreg); psum += p[j]; }
    psum += __shfl_xor(psum, 16);
    psum += __shfl_xor(psum, 32);
    lsum += psum;

    Frag pf;
    pf.u[0] = pk2r(p[0], p[1]); pf.u[1] = pk2r(p[2], p[3]);
    pf.u[2] = pk2r(p[4], p[5]); pf.u[3] = pk2r(p[6], p[7]);

    acc0 = __builtin_amdgcn_mfma_f32_16x16x32_bf16(pf.s8, v0.s8, acc0, 0, 0, 0);
    acc1 = __builtin_amdgcn_mfma_f32_16x16x32_bf16(pf.s8, v1.s8, acc1, 0, 0, 0);
    acc2 = __builtin_amdgcn_mfma_f32_16x16x32_bf16(pf.s8, v2.s8, acc2, 0, 0, 0);
    acc3 = __builtin_amdgcn_mfma_f32_16x16x32_bf16(pf.s8, v3.s8, acc3, 0, 0, 0);
  }

  // ---- merge parity-partner waves ----
  if (par == 1) {
    #pragma unroll
    for (int r = 0; r < 4; ++r) {
      const int row = 4 * l4 + r;
      oacc[w][row][li]      = acc0[r];
      oacc[w][row][16 + li] = acc1[r];
      oacc[w][row][32 + li] = acc2[r];
      oacc[w][row][48 + li] = acc3[r];
    }
    if (l4 == 0) { ml[w][0][li] = mreg; ml[w][1][li] = lsum; }
  }
  __syncthreads();
  if (par == 0) {
    const float m1 = ml[w + 1][0][li], l1 = ml[w + 1][1][li];
    const float ms = fmaxf(mreg, m1);
    float a0 = exp2f(mreg - ms), a1 = exp2f(m1 - ms);
    const float L = lsum * a0 + l1 * a1;
    const float inv = 1.0f / L;
    a0 *= inv; a1 *= inv;
    float* op = out + (size_t)(bT + q0) * 64;
    #pragma unroll
    for (int r = 0; r < 4; ++r) {
      const float w0 = __shfl(a0, 4 * l4 + r);
      const float w1 = __shfl(a1, 4 * l4 + r);
      const int row = 4 * l4 + r;
      op[row * 64 + li]      = acc0[r] * w0 + oacc[w + 1][row][li]      * w1;
      op[row * 64 + 16 + li] = acc1[r] * w0 + oacc[w + 1][row][16 + li] * w1;
      op[row * 64 + 32 + li] = acc2[r] * w0 + oacc[w + 1][row][32 + li] * w1;
      op[row * 64 + 48 + li] = acc3[r] * w0 + oacc[w + 1][row][48 + li] * w1;
    }
  }
}

// ---------------------------------------------------------------------------
extern "C" void kernel_launch(void* const* d_in, const int* in_sizes, int n_in,
                              void* d_out, int out_size, void* d_ws, size_t ws_size,
                              hipStream_t stream) {
  const float* x  = (const float*)d_in[0];
  const float* Wq = (const float*)d_in[1];
  const float* Wk = (const float*)d_in[2];
  const float* Wv = (const float*)d_in[3];
  float* outp = (float*)d_out;

  unsigned short* wt = (unsigned short*)d_ws;        // [3*64][1024]  = 196608
  unsigned short* qb = wt + 196608;                  // [BT][64]
  unsigned short* kb = qb + (size_t)BT * 64;         // [BT][64]
  unsigned short* vt = kb + (size_t)BT * 64;         // [64][BT]

  wcvt<<<192, 256, 0, stream>>>(Wq, Wk, Wv, wt);
  qkv_proj<<<512, 512, 0, stream>>>(x, wt, qb, kb, vt);
  attn_fwd<<<256, 512, 0, stream>>>(qb, kb, vt, outp);
}